// Round 4
// baseline (758.135 us; speedup 1.0000x reference)
//
#include <hip/hip_runtime.h>

// BaseTextureDiffusion: out[b,c,y,x] = sum_k w[b,c,k,y,x] * latent_pad[b,c,y+i,x+j]
// B=2 C=24 H=W=256 R=7 (replicate pad 3). Memory-bound on the 616 MB weights stream.
// Each thread computes 2 output rows x 4 px: per k, the two weight loads are
// back-to-back at addresses 1 KB apart -> each wave covers 2 KB contiguous,
// each block (TILE_H=8) covers 8 KB contiguous per k-slice. Bigger DRAM bursts
// on the 256KB-strided k-walk.

typedef float fx4 __attribute__((ext_vector_type(4)));   // nontemporal builtins need a true vector type

constexpr int Hh = 256, Ww = 256, Rr = 7, PAD = 3;
constexpr int TILE_H = 8;
constexpr int LW  = Ww + 2 * PAD;       // 262 valid cols (full width + halo)
constexpr int LWP = 264;                // padded stride, 264*4B multiple of 16
constexpr int LH  = TILE_H + 2 * PAD;   // 14 rows
constexpr int TILES_Y = Hh / TILE_H;    // 32
constexpr int PLANES  = 48;             // B*C

__global__ __launch_bounds__(256) void diffusion_kernel(
    const float* __restrict__ latent,
    const float* __restrict__ weights,
    float* __restrict__ out)
{
    __shared__ __align__(16) float lds[LH * LWP];   // 14.8 KB

    const int bid   = blockIdx.x;
    const int plane = bid / TILES_Y;                // b*C + c
    const int ty0   = (bid % TILES_Y) * TILE_H;

    const float* lat  = latent  + (size_t)plane * Hh * Ww;
    const float* wgt  = weights + (size_t)plane * (Rr * Rr) * Hh * Ww;
    float*       optr = out     + (size_t)plane * Hh * Ww;

    // Stage latent rows [ty0-3, ty0+TILE_H+3) with replicate clamping.
    for (int idx = threadIdx.x; idx < LH * LW; idx += 256) {
        const int ly = idx / LW;
        const int lx = idx - ly * LW;
        const int gy = min(max(ty0 + ly - PAD, 0), Hh - 1);
        const int gx = min(max(lx - PAD, 0), Ww - 1);
        lds[ly * LWP + lx] = lat[gy * Ww + gx];
    }
    __syncthreads();

    // Wave wv covers output rows ty0+2*wv and ty0+2*wv+1, full width.
    const int tx = threadIdx.x & 63;
    const int wv = threadIdx.x >> 6;    // 0..3
    const int x  = 4 * tx;
    const int y0 = ty0 + 2 * wv;

    const float* wbase = wgt + (size_t)y0 * Ww + x;

    fx4 acc0 = {0.f, 0.f, 0.f, 0.f};
    fx4 acc1 = {0.f, 0.f, 0.f, 0.f};

    #pragma unroll
    for (int i = 0; i < Rr; ++i) {
        // Input windows for the two output rows: lds rows (2wv+i) and (2wv+i+1).
        const float* lrow0 = &lds[(2 * wv + i) * LWP + x];
        const float* lrow1 = lrow0 + LWP;
        const float4 a0 = *(const float4*)(lrow0);
        const float4 b0 = *(const float4*)(lrow0 + 4);
        const float2 c0 = *(const float2*)(lrow0 + 8);
        const float4 a1 = *(const float4*)(lrow1);
        const float4 b1 = *(const float4*)(lrow1 + 4);
        const float2 c1 = *(const float2*)(lrow1 + 8);
        const float r0[10] = {a0.x, a0.y, a0.z, a0.w, b0.x, b0.y, b0.z, b0.w, c0.x, c0.y};
        const float r1[10] = {a1.x, a1.y, a1.z, a1.w, b1.x, b1.y, b1.z, b1.w, c1.x, c1.y};

        #pragma unroll
        for (int j = 0; j < Rr; ++j) {
            const int k = i * Rr + j;
            const fx4 w0 = __builtin_nontemporal_load(
                (const fx4*)(wbase + (size_t)k * (Hh * Ww)));
            const fx4 w1 = __builtin_nontemporal_load(
                (const fx4*)(wbase + (size_t)k * (Hh * Ww) + Ww));
            acc0.x += w0.x * r0[j + 0];
            acc0.y += w0.y * r0[j + 1];
            acc0.z += w0.z * r0[j + 2];
            acc0.w += w0.w * r0[j + 3];
            acc1.x += w1.x * r1[j + 0];
            acc1.y += w1.y * r1[j + 1];
            acc1.z += w1.z * r1[j + 2];
            acc1.w += w1.w * r1[j + 3];
        }
    }

    __builtin_nontemporal_store(acc0, (fx4*)(optr + (size_t)y0 * Ww + x));
    __builtin_nontemporal_store(acc1, (fx4*)(optr + (size_t)(y0 + 1) * Ww + x));
}

extern "C" void kernel_launch(void* const* d_in, const int* in_sizes, int n_in,
                              void* d_out, int out_size, void* d_ws, size_t ws_size,
                              hipStream_t stream) {
    const float* latent  = (const float*)d_in[0];
    const float* weights = (const float*)d_in[1];
    // d_in[2] = window_size (scalar int, fixed at 7) -- compiled in.
    float* out = (float*)d_out;

    const int nblocks = PLANES * TILES_Y;  // 1536
    diffusion_kernel<<<nblocks, 256, 0, stream>>>(latent, weights, out);
}